// Round 5
// baseline (229.831 us; speedup 1.0000x reference)
//
#include <hip/hip_runtime.h>
#include <hip/hip_bf16.h>
#include <math.h>

// B=64, M=1, L=E=4096, H=64, DK=64.
// Pure-streaming skinny GEMM: W (HBM, read once) -> regs, 2-chunk prefetch;
// A (1 MB hi+lo, L2-hot) -> regs as bf16x8 fragments, double-buffered.
// No LDS, no barriers, no inline asm: all hazards compiler-tracked.
// bf16 split-precision MFMA (hi/lo, 3 products).

#define TL 4096
#define NB 64
#define KSQ 4   // k-splits for QKV projections
#define KSO 8   // k-splits for output GEMM

typedef float f32x4 __attribute__((ext_vector_type(4)));
typedef short bf16x8 __attribute__((ext_vector_type(8)));
typedef unsigned int uint32;
typedef unsigned short u16;

union B8 { uint32 u[4]; bf16x8 v; };

// Split two fp32 into packed hi-bf16 pair and lo-bf16 pair (truncation).
__device__ __forceinline__ void split_pair(float f0, float f1, uint32& hp,
                                           uint32& lp) {
  uint32 u0 = __float_as_uint(f0), u1 = __float_as_uint(f1);
  hp = (u0 >> 16) | (u1 & 0xffff0000u);
  float l0 = f0 - __uint_as_float(u0 & 0xffff0000u);
  float l1 = f1 - __uint_as_float(u1 & 0xffff0000u);
  lp = (__float_as_uint(l0) >> 16) | (__float_as_uint(l1) & 0xffff0000u);
}

// ---------------------------------------------------------------------------
// prep: fp32 X[64][4096] -> Ah, Al bf16 (row-major)
// ---------------------------------------------------------------------------
struct Ptrs3 { const float* X[3]; u16* H[3]; u16* L[3]; };

__global__ __launch_bounds__(256) void prep_kernel(Ptrs3 p) {
  const int m = blockIdx.y;
  const int i = (blockIdx.x * 256 + threadIdx.x) * 4;
  const float4 f = *reinterpret_cast<const float4*>(p.X[m] + i);
  uint2 hv, lv;
  split_pair(f.x, f.y, hv.x, lv.x);
  split_pair(f.z, f.w, hv.y, lv.y);
  *reinterpret_cast<uint2*>(p.H[m] + i) = hv;
  *reinterpret_cast<uint2*>(p.L[m] + i) = lv;
}

// ---------------------------------------------------------------------------
// GEMM: P[ks][64][4096] partial = X[64][krange] @ W[krange][4096]
// Block: 8 waves (512 thr), 128 cols (16/wave), all 64 rows, KR = TL/KSplit.
// Chunk = K32. Per chunk per wave: 8 B dwords (HBM) + 8 A bf16x8 (L2).
// A frag (lane = l15 + 16*kg): row rt*16+l15, k = kg*8+e -> one 64B line
// per row across the 4 kg lanes. B frag: col = colg+l15, k = kg*8+e.
// ---------------------------------------------------------------------------
struct GemmArgs {
  const u16* Ah[3];
  const u16* Al[3];
  const float* W[3];
  float* P[3];
};

template <int KSplit, int NMat>
__global__ __launch_bounds__(512) void mfma_gemm(GemmArgs ga) {
  constexpr int KR = TL / KSplit;   // K range per block
  constexpr int NC = KR / 32;       // K32 chunks (32 or 16, even)
  constexpr int NWG = NMat * KSplit * 32;

  const int tid = threadIdx.x;
  const int lane = tid & 63;
  const int w = tid >> 6;                    // wave 0..7
  const int l15 = lane & 15, kg = lane >> 4;

  // Bijective XCD swizzle (NWG % 8 == 0): contiguous range per XCD so the
  // shared A slice (<= 2 matrices ~ 2 MB) stays resident in that XCD's L2.
  const int swz = (blockIdx.x & 7) * (NWG / 8) + (blockIdx.x >> 3);
  const int mat = swz / (KSplit * 32);
  const int r = swz % (KSplit * 32);
  const int ks = r / 32;
  const int ct = r & 31;
  const int k0 = ks * KR;
  const int colg = ct * 128 + w * 16;        // this wave's 16-col base

  const float* Wm = ga.W[mat];
  const u16* Agh = ga.Ah[mat];
  const u16* Agl = ga.Al[mat];

  // Per-lane bases (32-bit offsets from uniform pointers).
  const uint32 abase = (uint32)l15 * TL + (uint32)(k0 + kg * 8);
  const float* wp0 = Wm + (size_t)(k0 + kg * 8) * TL + colg + l15;

  auto LOADA = [&](bf16x8 (&h)[4], bf16x8 (&l)[4], int t) {
    const uint32 off = abase + (uint32)t * 32;
#pragma unroll
    for (int rt = 0; rt < 4; ++rt) {
      h[rt] = *(const bf16x8*)(Agh + off + (uint32)rt * 16 * TL);
      l[rt] = *(const bf16x8*)(Agl + off + (uint32)rt * 16 * TL);
    }
  };

  auto LOADB = [&](float (&f)[8], int t) {
    const float* wp = wp0 + (size_t)t * 32 * TL;
#pragma unroll
    for (int e = 0; e < 8; ++e) f[e] = wp[(size_t)e * TL];
  };

  f32x4 acc[4] = {};

  auto COMPUTE = [&](const bf16x8 (&h)[4], const bf16x8 (&l)[4],
                     const float (&f)[8]) {
    B8 bh, bl;
#pragma unroll
    for (int e = 0; e < 4; ++e)
      split_pair(f[2 * e], f[2 * e + 1], bh.u[e], bl.u[e]);
#pragma unroll
    for (int rt = 0; rt < 4; ++rt) {
      acc[rt] = __builtin_amdgcn_mfma_f32_16x16x32_bf16(h[rt], bh.v, acc[rt], 0, 0, 0);
      acc[rt] = __builtin_amdgcn_mfma_f32_16x16x32_bf16(h[rt], bl.v, acc[rt], 0, 0, 0);
      acc[rt] = __builtin_amdgcn_mfma_f32_16x16x32_bf16(l[rt], bh.v, acc[rt], 0, 0, 0);
    }
  };

  // Static double-buffered registers (rule #20: no runtime indexing).
  bf16x8 ah0[4], al0[4], ah1[4], al1[4];
  float b0[8], b1[8];

  LOADA(ah0, al0, 0); LOADB(b0, 0);
  LOADA(ah1, al1, 1); LOADB(b1, 1);

#pragma unroll 1
  for (int t = 0; t < NC - 2; t += 2) {
    COMPUTE(ah0, al0, b0);
    LOADA(ah0, al0, t + 2);
    LOADB(b0, t + 2);
    COMPUTE(ah1, al1, b1);
    LOADA(ah1, al1, t + 3);
    LOADB(b1, t + 3);
  }
  COMPUTE(ah0, al0, b0);
  COMPUTE(ah1, al1, b1);

  // C/D: col = lane&15, row = (lane>>4)*4 + reg (per 16-row tile rt)
  float* Pp = ga.P[mat] + ((size_t)ks * NB) * TL + colg + l15;
#pragma unroll
  for (int rt = 0; rt < 4; ++rt)
#pragma unroll
    for (int j = 0; j < 4; ++j)
      Pp[(size_t)(rt * 16 + kg * 4 + j) * TL] = acc[rt][j];
}

// ---------------------------------------------------------------------------
// dist[b,h] = softmax_h(cossim(qh[b,h,:], kh[b,h,:])); sums KSQ partials+bias.
// ---------------------------------------------------------------------------
__global__ __launch_bounds__(64) void dist_kernel(
    const float* __restrict__ Pq, const float* __restrict__ Pk,
    const float* __restrict__ bq, const float* __restrict__ bk,
    float* __restrict__ dist) {
  const int b = blockIdx.x;
  const int h = threadIdx.x;
  float num = 0.f, qq = 0.f, kk = 0.f;
#pragma unroll
  for (int d = 0; d < 64; d += 4) {
    f32x4 qv = *(const f32x4*)&bq[h * 64 + d];
    f32x4 kv = *(const f32x4*)&bk[h * 64 + d];
#pragma unroll
    for (int s = 0; s < KSQ; ++s) {
      qv += *(const f32x4*)&Pq[((size_t)s * NB + b) * TL + h * 64 + d];
      kv += *(const f32x4*)&Pk[((size_t)s * NB + b) * TL + h * 64 + d];
    }
#pragma unroll
    for (int e = 0; e < 4; ++e) {
      num += qv[e] * kv[e];
      qq += qv[e] * qv[e];
      kk += kv[e] * kv[e];
    }
  }
  const float den = fmaxf(sqrtf(qq) * sqrtf(kk), 1e-8f);
  float s = num / den;
  float m = s;
#pragma unroll
  for (int off = 32; off; off >>= 1) m = fmaxf(m, __shfl_xor(m, off));
  const float e = expf(s - m);
  float sum = e;
#pragma unroll
  for (int off = 32; off; off >>= 1) sum += __shfl_xor(sum, off);
  dist[b * 64 + h] = e / sum;
}

// ---------------------------------------------------------------------------
// attn row i: vrow = sum(Pv parts)+bv; attn[i,j*64+d] = sum_h ds[j,h]*vrow[..]
// Emits hi/lo bf16 (A-operand of the output GEMM).
// ---------------------------------------------------------------------------
__global__ __launch_bounds__(256) void attn_kernel(
    const float* __restrict__ Pv, const float* __restrict__ bv,
    const float* __restrict__ dist, u16* __restrict__ Ah,
    u16* __restrict__ Al) {
  const int i = blockIdx.x;
  __shared__ float vrow[TL];
  __shared__ float ds[NB * NB];
  const int tid = threadIdx.x;
#pragma unroll
  for (int f = tid; f < 1024; f += 256) {
    f32x4 v = *(const f32x4*)&bv[f * 4];
#pragma unroll
    for (int s = 0; s < KSQ; ++s)
      v += *(const f32x4*)&Pv[((size_t)s * NB + i) * TL + f * 4];
    *reinterpret_cast<f32x4*>(&vrow[f * 4]) = v;
    *reinterpret_cast<f32x4*>(&ds[f * 4]) =
        *reinterpret_cast<const f32x4*>(&dist[f * 4]);
  }
  __syncthreads();
#pragma unroll
  for (int s = 0; s < 16; ++s) {
    const int c = tid + 256 * s;
    const int j = c >> 6, d = c & 63;
    float sum = 0.f;
#pragma unroll
    for (int h = 0; h < 64; ++h) sum += ds[j * 64 + h] * vrow[h * 64 + d];
    const uint32 u = __float_as_uint(sum);
    const float lo = sum - __uint_as_float(u & 0xffff0000u);
    Ah[i * TL + c] = (u16)(u >> 16);
    Al[i * TL + c] = (u16)(__float_as_uint(lo) >> 16);
  }
}

// out = sum over KSO partials + bo
__global__ __launch_bounds__(256) void reduce_kernel(
    const float* __restrict__ Po, const float* __restrict__ bo,
    float* __restrict__ out) {
  const int idx = (blockIdx.x * 256 + threadIdx.x) * 4;
  f32x4 v = *(const f32x4*)&bo[idx & (TL - 1)];
#pragma unroll
  for (int s = 0; s < KSO; ++s)
    v += *(const f32x4*)&Po[(size_t)s * NB * TL + idx];
  *reinterpret_cast<f32x4*>(&out[idx]) = v;
}

extern "C" void kernel_launch(void* const* d_in, const int* in_sizes, int n_in,
                              void* d_out, int out_size, void* d_ws,
                              size_t ws_size, hipStream_t stream) {
  const float* q  = (const float*)d_in[0];
  const float* k  = (const float*)d_in[1];
  const float* v  = (const float*)d_in[2];
  const float* Wq = (const float*)d_in[3];
  const float* bq = (const float*)d_in[4];
  const float* Wk = (const float*)d_in[5];
  const float* bk = (const float*)d_in[6];
  const float* Wv = (const float*)d_in[7];
  const float* bv = (const float*)d_in[8];
  const float* Wo = (const float*)d_in[9];
  const float* bo = (const float*)d_in[10];
  float* out = (float*)d_out;

  char* ws = (char*)d_ws;
  const size_t HB = 512u * 1024u;
  u16* qAh = (u16*)(ws + 0 * HB);
  u16* qAl = (u16*)(ws + 1 * HB);
  u16* kAh = (u16*)(ws + 2 * HB);
  u16* kAl = (u16*)(ws + 3 * HB);
  u16* vAh = (u16*)(ws + 4 * HB);
  u16* vAl = (u16*)(ws + 5 * HB);
  u16* aAh = (u16*)(ws + 6 * HB);
  u16* aAl = (u16*)(ws + 7 * HB);
  float* Pq = (float*)(ws + (4u << 20));   // 4 MiB (KSQ=4 partials)
  float* Pk = (float*)(ws + (8u << 20));   // 4 MiB
  float* Pv = (float*)(ws + (12u << 20));  // 4 MiB
  // Po (KSO=8, 8 MiB) aliases [Pq,Pk]: both fully consumed by dist_kernel
  // before the output GEMM runs. Rewritten every launch -> deterministic.
  float* Po = Pq;
  float* dist = (float*)(ws + (16u << 20));  // 16 KiB

  // 1. split q,k,v into hi/lo bf16
  Ptrs3 p3;
  p3.X[0] = q; p3.X[1] = k; p3.X[2] = v;
  p3.H[0] = qAh; p3.H[1] = kAh; p3.H[2] = vAh;
  p3.L[0] = qAl; p3.L[1] = kAl; p3.L[2] = vAl;
  prep_kernel<<<dim3(256, 3), 256, 0, stream>>>(p3);

  // 2. QKV projections: 3 mats x KSQ ksplits x 32 coltiles = 384 blocks
  GemmArgs gq;
  gq.Ah[0] = qAh; gq.Ah[1] = kAh; gq.Ah[2] = vAh;
  gq.Al[0] = qAl; gq.Al[1] = kAl; gq.Al[2] = vAl;
  gq.W[0] = Wq; gq.W[1] = Wk; gq.W[2] = Wv;
  gq.P[0] = Pq; gq.P[1] = Pk; gq.P[2] = Pv;
  mfma_gemm<KSQ, 3><<<3 * KSQ * 32, 512, 0, stream>>>(gq);

  // 3. cosine-sim + softmax
  dist_kernel<<<NB, 64, 0, stream>>>(Pq, Pk, bq, bk, dist);

  // 4. attention mix -> bf16 hi/lo attn
  attn_kernel<<<NB, 256, 0, stream>>>(Pv, bv, dist, aAh, aAl);

  // 5. output GEMM: KSO ksplits x 32 coltiles = 256 blocks
  GemmArgs go;
  go.Ah[0] = aAh; go.Ah[1] = aAh; go.Ah[2] = aAh;
  go.Al[0] = aAl; go.Al[1] = aAl; go.Al[2] = aAl;
  go.W[0] = Wo; go.W[1] = Wo; go.W[2] = Wo;
  go.P[0] = Po; go.P[1] = Po; go.P[2] = Po;
  mfma_gemm<KSO, 1><<<KSO * 32, 512, 0, stream>>>(go);

  // 6. final reduce + bias
  reduce_kernel<<<256, 256, 0, stream>>>(Po, bo, out);
}